// Round 5
// baseline (1523.000 us; speedup 1.0000x reference)
//
#include <hip/hip_runtime.h>
#include <math.h>

// Problem constants (fixed by the reference)
#define LAYERS 6
#define BB 4
#define NN 23890
#define KTOK 1024
#define DD 256
#define NH 8
#define HDIM 32
#define FFND 1024
#define NCLS 15
#define MROWS (BB*KTOK)   // 4096

typedef __attribute__((ext_vector_type(8))) short bf16x8;
typedef __attribute__((ext_vector_type(4))) float f32x4;

__device__ __forceinline__ unsigned short f2bf(float x) {
    unsigned u = __float_as_uint(x);
    u += 0x7fffu + ((u >> 16) & 1u);          // RNE
    return (unsigned short)(u >> 16);
}

// ---------------------------------------------------------------------------
// Block-wide sum over 256 threads (4 waves)
// ---------------------------------------------------------------------------
__device__ __forceinline__ float block_sum256(float v) {
    __shared__ float sh[4];
    #pragma unroll
    for (int o = 32; o; o >>= 1) v += __shfl_xor(v, o);
    const int lane = threadIdx.x & 63, w = threadIdx.x >> 6;
    __syncthreads();            // protect sh[] across back-to-back calls
    if (lane == 0) sh[w] = v;
    __syncthreads();
    return sh[0] + sh[1] + sh[2] + sh[3];
}

// ---------------------------------------------------------------------------
// One-time per call: W[L][K][N] (f32) -> Wt[L][N][K] (bf16), 32x32 LDS tiles
// grid: (Nd/32, Kd/32, LAYERS), block 256
// ---------------------------------------------------------------------------
__global__ __launch_bounds__(256) void transpose_cast_k(
    const float* __restrict__ W, unsigned short* __restrict__ Wt,
    int Kd, int Nd)
{
    __shared__ float tile[32][33];
    const int n0 = blockIdx.x * 32, k0 = blockIdx.y * 32;
    const size_t loff = (size_t)blockIdx.z * Kd * Nd;
    const int t = threadIdx.x;
    const int r = t >> 3, c = (t & 7) * 4;
    const float4 v = *(const float4*)&W[loff + (size_t)(k0 + r) * Nd + n0 + c];
    tile[r][c + 0] = v.x; tile[r][c + 1] = v.y;
    tile[r][c + 2] = v.z; tile[r][c + 3] = v.w;
    __syncthreads();
    ushort4 p;
    p.x = f2bf(tile[c + 0][r]);
    p.y = f2bf(tile[c + 1][r]);
    p.z = f2bf(tile[c + 2][r]);
    p.w = f2bf(tile[c + 3][r]);
    *(ushort4*)&Wt[loff + (size_t)(n0 + r) * Kd + k0 + c] = p;
}

// ---------------------------------------------------------------------------
// Gather + MCSP score modulation:  tgt = q*mc (f32+bf16),  qk_bf = bf16(tgt+qpos)
// one block (256 thr) per (b,k) row
// ---------------------------------------------------------------------------
__global__ __launch_bounds__(256) void gather_k(
    const float* __restrict__ outp, const float* __restrict__ qpos,
    const float* __restrict__ fg, const int* __restrict__ inds,
    const float* __restrict__ Wcls, const float* __restrict__ bcls,
    float* __restrict__ tgt, unsigned short* __restrict__ tgt_bf,
    unsigned short* __restrict__ qk_bf)
{
    const int row = blockIdx.x, t = threadIdx.x;
    const int b = row >> 10;
    const int k = row & 1023;
    const int ind = inds[b * KTOK + k];
    __shared__ float qs[DD];
    __shared__ float sco[NCLS];
    __shared__ float mcsh;
    const size_t src = ((size_t)b * NN + ind) * DD + t;
    const float qv = outp[src];
    qs[t] = qv;
    __syncthreads();
    if (t < NCLS) {
        float s = bcls[t];
        #pragma unroll 8
        for (int d = 0; d < DD; ++d) s = fmaf(qs[d], Wcls[d * NCLS + t], s);
        sco[t] = s;
    }
    __syncthreads();
    if (t == 0) {
        float m = sco[0];
        #pragma unroll
        for (int j = 1; j < NCLS; ++j) m = fmaxf(m, sco[j]);
        // max(sigmoid(s)) == sigmoid(max(s)) (monotonic)
        mcsh = fg[(size_t)b * NN + ind] / (1.0f + expf(-m));
    }
    __syncthreads();
    const float tv = qv * mcsh;
    const size_t off = (size_t)row * DD + t;
    tgt[off] = tv;
    tgt_bf[off] = f2bf(tv);
    qk_bf[off] = f2bf(tv + qpos[src]);
}

// ---------------------------------------------------------------------------
// MFMA GEMM body: C[4096,Nsz] = A_bf16[4096,Ksz] @ Wt_bf16[Nsz,Ksz]^T + bias
// BM=BN=64, BK=32, 256 threads (4 waves), each wave one 32x32 quadrant
// (2x2 mfma_f32_16x16x32_bf16 tiles). Outputs f32 and/or bf16.
// ---------------------------------------------------------------------------
__device__ __forceinline__ void mgemm_body(
    const unsigned short* __restrict__ A, const unsigned short* __restrict__ Wt,
    const float* __restrict__ bias, float* __restrict__ Cf,
    unsigned short* __restrict__ Cb, int Nsz, int Ksz, bool relu,
    int bm, int bn)
{
    __shared__ unsigned short As[64 * 32];
    __shared__ unsigned short Bs[64 * 32];
    const int t = threadIdx.x;
    const int lane = t & 63, wave = t >> 6;
    const int ln15 = lane & 15, kg = lane >> 4;      // operand row/col, k-group
    const int wm = (wave >> 1) * 32, wn = (wave & 1) * 32;
    const int sr = t >> 2, sc = (t & 3) * 8;         // staging coords

    f32x4 acc[2][2];
    #pragma unroll
    for (int i = 0; i < 2; ++i)
        #pragma unroll
        for (int j = 0; j < 2; ++j) acc[i][j] = (f32x4)0.0f;

    for (int k0 = 0; k0 < Ksz; k0 += 32) {
        *(bf16x8*)&As[sr * 32 + sc] =
            *(const bf16x8*)&A[(size_t)(bm + sr) * Ksz + k0 + sc];
        *(bf16x8*)&Bs[sr * 32 + sc] =
            *(const bf16x8*)&Wt[(size_t)(bn + sr) * Ksz + k0 + sc];
        __syncthreads();
        const bf16x8 a0 = *(const bf16x8*)&As[(wm + ln15) * 32 + kg * 8];
        const bf16x8 a1 = *(const bf16x8*)&As[(wm + 16 + ln15) * 32 + kg * 8];
        const bf16x8 b0 = *(const bf16x8*)&Bs[(wn + ln15) * 32 + kg * 8];
        const bf16x8 b1 = *(const bf16x8*)&Bs[(wn + 16 + ln15) * 32 + kg * 8];
        acc[0][0] = __builtin_amdgcn_mfma_f32_16x16x32_bf16(a0, b0, acc[0][0], 0, 0, 0);
        acc[0][1] = __builtin_amdgcn_mfma_f32_16x16x32_bf16(a0, b1, acc[0][1], 0, 0, 0);
        acc[1][0] = __builtin_amdgcn_mfma_f32_16x16x32_bf16(a1, b0, acc[1][0], 0, 0, 0);
        acc[1][1] = __builtin_amdgcn_mfma_f32_16x16x32_bf16(a1, b1, acc[1][1], 0, 0, 0);
        __syncthreads();
    }

    #pragma unroll
    for (int mt = 0; mt < 2; ++mt) {
        #pragma unroll
        for (int nt = 0; nt < 2; ++nt) {
            const int col = bn + wn + nt * 16 + ln15;
            const int r0  = bm + wm + mt * 16 + kg * 4;
            const float bv = bias[col];
            #pragma unroll
            for (int j = 0; j < 4; ++j) {
                float v = acc[mt][nt][j] + bv;
                if (relu) v = fmaxf(v, 0.0f);
                const size_t o = (size_t)(r0 + j) * Nsz + col;
                if (Cf) Cf[o] = v;
                if (Cb) Cb[o] = f2bf(v);
            }
        }
    }
}

__global__ __launch_bounds__(256) void mgemm_k(
    const unsigned short* __restrict__ A, const unsigned short* __restrict__ Wt,
    const float* __restrict__ bias, float* __restrict__ Cf,
    unsigned short* __restrict__ Cb, int Nsz, int Ksz, int relu)
{
    mgemm_body(A, Wt, bias, Cf, Cb, Nsz, Ksz, relu != 0,
               blockIdx.y * 64, blockIdx.x * 64);
}

// Q,K,V in one launch (blockIdx.z selects)
__global__ __launch_bounds__(256) void mgemm_qkv_k(
    const unsigned short* __restrict__ qk_bf, const unsigned short* __restrict__ tgt_bf,
    const unsigned short* __restrict__ wqt, const float* __restrict__ bq,
    const unsigned short* __restrict__ wkt, const float* __restrict__ bk,
    const unsigned short* __restrict__ wvt, const float* __restrict__ bv,
    float* __restrict__ Qb, float* __restrict__ Kb, float* __restrict__ Vb)
{
    const unsigned short* A; const unsigned short* W; const float* bi; float* C;
    if (blockIdx.z == 0)      { A = qk_bf;  W = wqt; bi = bq; C = Qb; }
    else if (blockIdx.z == 1) { A = qk_bf;  W = wkt; bi = bk; C = Kb; }
    else                      { A = tgt_bf; W = wvt; bi = bv; C = Vb; }
    mgemm_body(A, W, bi, C, nullptr, DD, DD, false,
               blockIdx.y * 64, blockIdx.x * 64);
}

// ---------------------------------------------------------------------------
// Flash-style attention (fp32 vector path): one block per (qtile=64, head, batch)
// Q,K,V fp32 [B*K, 256] (col = h*32 + d); output written as bf16
// ---------------------------------------------------------------------------
__global__ __launch_bounds__(256) void attn_k(
    const float* __restrict__ Qb, const float* __restrict__ Kb,
    const float* __restrict__ Vb, unsigned short* __restrict__ Ob)
{
    const int qt = blockIdx.x;   // 0..15
    const int h  = blockIdx.y;   // 0..7
    const int b  = blockIdx.z;   // 0..3
    const int t  = threadIdx.x;
    const int r4 = t >> 4;       // 0..15 : rows r4*4+i
    const int c4 = t & 15;       // 0..15 : S cols c4*4+j ; O cols c4*2..+1
    __shared__ float Qs[64][36];
    __shared__ float Ks[64][36];
    __shared__ float Vs[64][36];
    __shared__ float Ps[64][68];
    const float scale = 0.17677669529663687f;  // 1/sqrt(32)

    {   // load Q tile (64 x 32), 8 floats/thread
        const int rowi = t >> 2, d0 = (t & 3) * 8;
        const float* src = &Qb[((size_t)(b * KTOK + qt * 64 + rowi)) * DD + h * HDIM + d0];
        *(float4*)&Qs[rowi][d0]     = *(const float4*)(src);
        *(float4*)&Qs[rowi][d0 + 4] = *(const float4*)(src + 4);
    }
    float m_i[4], l_i[4], accO[4][2];
    #pragma unroll
    for (int i = 0; i < 4; ++i) {
        m_i[i] = -1e30f; l_i[i] = 0.f; accO[i][0] = 0.f; accO[i][1] = 0.f;
    }

    for (int kt = 0; kt < 16; ++kt) {
        __syncthreads();   // previous iteration's readers done (also covers Q load)
        {
            const int rowi = t >> 2, d0 = (t & 3) * 8;
            const size_t base = ((size_t)(b * KTOK + kt * 64 + rowi)) * DD + h * HDIM + d0;
            *(float4*)&Ks[rowi][d0]     = *(const float4*)(&Kb[base]);
            *(float4*)&Ks[rowi][d0 + 4] = *(const float4*)(&Kb[base + 4]);
            *(float4*)&Vs[rowi][d0]     = *(const float4*)(&Vb[base]);
            *(float4*)&Vs[rowi][d0 + 4] = *(const float4*)(&Vb[base + 4]);
        }
        __syncthreads();
        // S = (Q Kt) * scale : 4x4 per thread
        float sv[4][4];
        #pragma unroll
        for (int i = 0; i < 4; ++i)
            #pragma unroll
            for (int j = 0; j < 4; ++j) sv[i][j] = 0.f;
        #pragma unroll
        for (int dd = 0; dd < 32; dd += 4) {
            float4 a[4], kb[4];
            #pragma unroll
            for (int i = 0; i < 4; ++i) a[i]  = *(const float4*)&Qs[r4 * 4 + i][dd];
            #pragma unroll
            for (int j = 0; j < 4; ++j) kb[j] = *(const float4*)&Ks[c4 * 4 + j][dd];
            #pragma unroll
            for (int i = 0; i < 4; ++i)
                #pragma unroll
                for (int j = 0; j < 4; ++j)
                    sv[i][j] += a[i].x * kb[j].x + a[i].y * kb[j].y +
                                a[i].z * kb[j].z + a[i].w * kb[j].w;
        }
        // online softmax per row
        #pragma unroll
        for (int i = 0; i < 4; ++i) {
            float rowm = -1e30f;
            #pragma unroll
            for (int j = 0; j < 4; ++j) { sv[i][j] *= scale; rowm = fmaxf(rowm, sv[i][j]); }
            #pragma unroll
            for (int o = 1; o < 16; o <<= 1) rowm = fmaxf(rowm, __shfl_xor(rowm, o));
            const float mnew = fmaxf(m_i[i], rowm);
            const float alpha = expf(m_i[i] - mnew);
            float ls = 0.f;
            #pragma unroll
            for (int j = 0; j < 4; ++j) { sv[i][j] = expf(sv[i][j] - mnew); ls += sv[i][j]; }
            #pragma unroll
            for (int o = 1; o < 16; o <<= 1) ls += __shfl_xor(ls, o);
            l_i[i] = l_i[i] * alpha + ls;
            m_i[i] = mnew;
            accO[i][0] *= alpha; accO[i][1] *= alpha;
            *(float4*)&Ps[r4 * 4 + i][c4 * 4] = *(float4*)&sv[i][0];
        }
        __syncthreads();
        // O += P @ V : rows r4*4+i, cols c4*2, c4*2+1
        #pragma unroll
        for (int kk = 0; kk < 64; kk += 4) {
            float v0[4], v1[4];
            #pragma unroll
            for (int x = 0; x < 4; ++x) {
                const float2 vv = *(const float2*)&Vs[kk + x][c4 * 2];
                v0[x] = vv.x; v1[x] = vv.y;
            }
            #pragma unroll
            for (int i = 0; i < 4; ++i) {
                const float4 p = *(const float4*)&Ps[r4 * 4 + i][kk];
                accO[i][0] += p.x * v0[0] + p.y * v0[1] + p.z * v0[2] + p.w * v0[3];
                accO[i][1] += p.x * v1[0] + p.y * v1[1] + p.z * v1[2] + p.w * v1[3];
            }
        }
    }
    #pragma unroll
    for (int i = 0; i < 4; ++i) {
        const int rowi = r4 * 4 + i;
        const float inv = 1.0f / l_i[i];
        ushort2 o2;
        o2.x = f2bf(accO[i][0] * inv);
        o2.y = f2bf(accO[i][1] * inv);
        *(ushort2*)&Ob[((size_t)(b * KTOK + qt * 64 + rowi)) * DD + h * HDIM + c4 * 2] = o2;
    }
}

// ---------------------------------------------------------------------------
// x = LayerNorm(A + B) * g + be       (one block per row), f32 + bf16 out
// ---------------------------------------------------------------------------
__global__ __launch_bounds__(256) void add_ln_k(
    const float* __restrict__ A, const float* __restrict__ Bv,
    const float* __restrict__ g, const float* __restrict__ be,
    float* __restrict__ outp, unsigned short* __restrict__ outp_bf)
{
    const int row = blockIdx.x, t = threadIdx.x;
    const size_t off = (size_t)row * DD + t;
    const float v = A[off] + Bv[off];
    const float mu = block_sum256(v) * (1.0f / DD);
    const float d = v - mu;
    const float var = block_sum256(d * d) * (1.0f / DD);
    const float r = d * rsqrtf(var + 1e-5f) * g[t] + be[t];
    outp[off] = r;
    outp_bf[off] = f2bf(r);
}

// LayerNorm(X + F) then ragged scatter into output
__global__ __launch_bounds__(256) void ln_scatter_k(
    const float* __restrict__ X, const float* __restrict__ F,
    const float* __restrict__ g, const float* __restrict__ be,
    const int* __restrict__ inds, const int* __restrict__ focus,
    float* __restrict__ outp)
{
    const int row = blockIdx.x, t = threadIdx.x;
    const int b = row >> 10;
    const int k = row & 1023;
    if (k >= focus[b]) return;   // uniform per block
    const size_t off = (size_t)row * DD + t;
    const float v = X[off] + F[off];
    const float mu = block_sum256(v) * (1.0f / DD);
    const float d = v - mu;
    const float var = block_sum256(d * d) * (1.0f / DD);
    const int ind = inds[b * KTOK + k];
    outp[((size_t)b * NN + ind) * DD + t] = d * rsqrtf(var + 1e-5f) * g[t] + be[t];
}

// ---------------------------------------------------------------------------
extern "C" void kernel_launch(void* const* d_in, const int* in_sizes, int n_in,
                              void* d_out, int out_size, void* d_ws, size_t ws_size,
                              hipStream_t stream)
{
    const float* query = (const float*)d_in[0];
    const float* qpos  = (const float*)d_in[1];
    // d_in[2..5]: spatial_shapes / level_start_index / valid_ratios / padding mask: unused
    const float* fg    = (const float*)d_in[6];
    const int*   focus = (const int*)d_in[7];
    const int*   finds = (const int*)d_in[8];
    const float* Wq = (const float*)d_in[9];  const float* bq = (const float*)d_in[10];
    const float* Wk = (const float*)d_in[11]; const float* bk = (const float*)d_in[12];
    const float* Wv = (const float*)d_in[13]; const float* bv = (const float*)d_in[14];
    const float* Wo = (const float*)d_in[15]; const float* bo = (const float*)d_in[16];
    const float* g1 = (const float*)d_in[17]; const float* be1 = (const float*)d_in[18];
    const float* W1 = (const float*)d_in[19]; const float* b1 = (const float*)d_in[20];
    const float* W2 = (const float*)d_in[21]; const float* b2 = (const float*)d_in[22];
    const float* g2 = (const float*)d_in[23]; const float* be2 = (const float*)d_in[24];
    const float* Wcls = (const float*)d_in[25]; const float* bcls = (const float*)d_in[26];
    float* out = (float*)d_out;

    // ---- workspace layout (bytes), all 16B-aligned chunks -----------------
    char* p = (char*)d_ws;
    const size_t MD4 = (size_t)MROWS * DD * 4;       // 4 MB
    const size_t MD2 = (size_t)MROWS * DD * 2;       // 2 MB
    float* tgt  = (float*)p;            p += MD4;
    float* Qb   = (float*)p;            p += MD4;    // reused as x
    float* Kb   = (float*)p;            p += MD4;    // reused as ff2
    float* Vb   = (float*)p;            p += MD4;    // reused as olin
    unsigned short* tgt_bf   = (unsigned short*)p;  p += MD2;
    unsigned short* qk_bf    = (unsigned short*)p;  p += MD2;
    unsigned short* attno_bf = (unsigned short*)p;  p += MD2;
    unsigned short* x_bf     = (unsigned short*)p;  p += MD2;
    unsigned short* ff1_bf   = (unsigned short*)p;  p += (size_t)MROWS * FFND * 2;  // 8 MB
    const size_t WSQ = (size_t)LAYERS * DD * DD;     // 393216 elems
    const size_t WFF = (size_t)LAYERS * DD * FFND;   // 1572864 elems
    unsigned short* wqt = (unsigned short*)p;  p += WSQ * 2;
    unsigned short* wkt = (unsigned short*)p;  p += WSQ * 2;
    unsigned short* wvt = (unsigned short*)p;  p += WSQ * 2;
    unsigned short* wot = (unsigned short*)p;  p += WSQ * 2;
    unsigned short* w1t = (unsigned short*)p;  p += WFF * 2;
    unsigned short* w2t = (unsigned short*)p;  p += WFF * 2;
    float* x    = Qb;     // Qb dead after attention
    float* olin = Vb;     // Vb dead after attention
    float* ff2  = Kb;     // Kb dead after attention

    // one-time weight transposes to bf16 Wt[N][K]
    transpose_cast_k<<<dim3(DD / 32, DD / 32, LAYERS), 256, 0, stream>>>(Wq, wqt, DD, DD);
    transpose_cast_k<<<dim3(DD / 32, DD / 32, LAYERS), 256, 0, stream>>>(Wk, wkt, DD, DD);
    transpose_cast_k<<<dim3(DD / 32, DD / 32, LAYERS), 256, 0, stream>>>(Wv, wvt, DD, DD);
    transpose_cast_k<<<dim3(DD / 32, DD / 32, LAYERS), 256, 0, stream>>>(Wo, wot, DD, DD);
    transpose_cast_k<<<dim3(FFND / 32, DD / 32, LAYERS), 256, 0, stream>>>(W1, w1t, DD, FFND);
    transpose_cast_k<<<dim3(DD / 32, FFND / 32, LAYERS), 256, 0, stream>>>(W2, w2t, FFND, DD);

    // output starts as query
    hipMemcpyAsync(out, query, (size_t)BB * NN * DD * sizeof(float),
                   hipMemcpyDeviceToDevice, stream);

    for (int l = 0; l < LAYERS; ++l) {
        const int* inds = finds + (size_t)l * BB * KTOK;
        gather_k<<<MROWS, 256, 0, stream>>>(out, qpos, fg, inds, Wcls, bcls,
                                            tgt, tgt_bf, qk_bf);
        mgemm_qkv_k<<<dim3(DD / 64, MROWS / 64, 3), 256, 0, stream>>>(
            qk_bf, tgt_bf,
            wqt + (size_t)l * DD * DD, bq + (size_t)l * DD,
            wkt + (size_t)l * DD * DD, bk + (size_t)l * DD,
            wvt + (size_t)l * DD * DD, bv + (size_t)l * DD,
            Qb, Kb, Vb);
        attn_k<<<dim3(KTOK / 64, NH, BB), 256, 0, stream>>>(Qb, Kb, Vb, attno_bf);
        mgemm_k<<<dim3(DD / 64, MROWS / 64), 256, 0, stream>>>(
            attno_bf, wot + (size_t)l * DD * DD, bo + (size_t)l * DD,
            olin, nullptr, DD, DD, 0);
        add_ln_k<<<MROWS, 256, 0, stream>>>(tgt, olin,
            g1 + (size_t)l * DD, be1 + (size_t)l * DD, x, x_bf);
        mgemm_k<<<dim3(FFND / 64, MROWS / 64), 256, 0, stream>>>(
            x_bf, w1t + (size_t)l * DD * FFND, b1 + (size_t)l * FFND,
            nullptr, ff1_bf, FFND, DD, 1);
        mgemm_k<<<dim3(DD / 64, MROWS / 64), 256, 0, stream>>>(
            ff1_bf, w2t + (size_t)l * DD * FFND, b2 + (size_t)l * DD,
            ff2, nullptr, DD, FFND, 0);
        ln_scatter_k<<<MROWS, 256, 0, stream>>>(x, ff2,
            g2 + (size_t)l * DD, be2 + (size_t)l * DD, inds, focus, out);
    }
    (void)in_sizes; (void)n_in; (void)out_size; (void)ws_size;
}

// Round 6
// 958.011 us; speedup vs baseline: 1.5898x; 1.5898x over previous
//
#include <hip/hip_runtime.h>
#include <math.h>

// Problem constants (fixed by the reference)
#define LAYERS 6
#define BB 4
#define NN 23890
#define KTOK 1024
#define DD 256
#define NH 8
#define HDIM 32
#define FFND 1024
#define NCLS 15
#define MROWS (BB*KTOK)   // 4096

typedef __attribute__((ext_vector_type(8))) short bf16x8;
typedef __attribute__((ext_vector_type(4))) float f32x4;

__device__ __forceinline__ unsigned short f2bf(float x) {
    unsigned u = __float_as_uint(x);
    u += 0x7fffu + ((u >> 16) & 1u);          // RNE
    return (unsigned short)(u >> 16);
}

// ---------------------------------------------------------------------------
// Block-wide sum over 256 threads (4 waves)
// ---------------------------------------------------------------------------
__device__ __forceinline__ float block_sum256(float v) {
    __shared__ float sh[4];
    #pragma unroll
    for (int o = 32; o; o >>= 1) v += __shfl_xor(v, o);
    const int lane = threadIdx.x & 63, w = threadIdx.x >> 6;
    __syncthreads();            // protect sh[] across back-to-back calls
    if (lane == 0) sh[w] = v;
    __syncthreads();
    return sh[0] + sh[1] + sh[2] + sh[3];
}

// ---------------------------------------------------------------------------
// One-time per call: W[L][K][N] (f32) -> Wt[L][N][K] (bf16), 32x32 LDS tiles
// ---------------------------------------------------------------------------
__global__ __launch_bounds__(256) void transpose_cast_k(
    const float* __restrict__ W, unsigned short* __restrict__ Wt,
    int Kd, int Nd)
{
    __shared__ float tile[32][33];
    const int n0 = blockIdx.x * 32, k0 = blockIdx.y * 32;
    const size_t loff = (size_t)blockIdx.z * Kd * Nd;
    const int t = threadIdx.x;
    const int r = t >> 3, c = (t & 7) * 4;
    const float4 v = *(const float4*)&W[loff + (size_t)(k0 + r) * Nd + n0 + c];
    tile[r][c + 0] = v.x; tile[r][c + 1] = v.y;
    tile[r][c + 2] = v.z; tile[r][c + 3] = v.w;
    __syncthreads();
    ushort4 p;
    p.x = f2bf(tile[c + 0][r]);
    p.y = f2bf(tile[c + 1][r]);
    p.z = f2bf(tile[c + 2][r]);
    p.w = f2bf(tile[c + 3][r]);
    *(ushort4*)&Wt[loff + (size_t)(n0 + r) * Kd + k0 + c] = p;
}

// ---------------------------------------------------------------------------
// Gather + MCSP:  tgt = q*mc (f32+bf16),  qk_bf = bf16(tgt + qpos)
// ---------------------------------------------------------------------------
__global__ __launch_bounds__(256) void gather_k(
    const float* __restrict__ outp, const float* __restrict__ qpos,
    const float* __restrict__ fg, const int* __restrict__ inds,
    const float* __restrict__ Wcls, const float* __restrict__ bcls,
    float* __restrict__ tgt, unsigned short* __restrict__ tgt_bf,
    unsigned short* __restrict__ qk_bf)
{
    const int row = blockIdx.x, t = threadIdx.x;
    const int b = row >> 10;
    const int k = row & 1023;
    const int ind = inds[b * KTOK + k];
    __shared__ float qs[DD];
    __shared__ float sco[NCLS];
    __shared__ float mcsh;
    const size_t src = ((size_t)b * NN + ind) * DD + t;
    const float qv = outp[src];
    qs[t] = qv;
    __syncthreads();
    if (t < NCLS) {
        float s = bcls[t];
        #pragma unroll 8
        for (int d = 0; d < DD; ++d) s = fmaf(qs[d], Wcls[d * NCLS + t], s);
        sco[t] = s;
    }
    __syncthreads();
    if (t == 0) {
        float m = sco[0];
        #pragma unroll
        for (int j = 1; j < NCLS; ++j) m = fmaxf(m, sco[j]);
        mcsh = fg[(size_t)b * NN + ind] / (1.0f + expf(-m));
    }
    __syncthreads();
    const float tv = qv * mcsh;
    const size_t off = (size_t)row * DD + t;
    tgt[off] = tv;
    tgt_bf[off] = f2bf(tv);
    qk_bf[off] = f2bf(tv + qpos[src]);
}

// ---------------------------------------------------------------------------
// MFMA GEMM body: C[4096,Nsz] = A_bf16 @ Wt_bf16^T + bias
// BM=BN=64, BK=32, 4 waves, 2x2 mfma 16x16x32 per wave.
// Outputs: f32 (Cf) and/or bf16 (Cb) and/or V-transposed bf16 (VtO).
// ---------------------------------------------------------------------------
__device__ __forceinline__ void mgemm_body(
    const unsigned short* __restrict__ A, const unsigned short* __restrict__ Wt,
    const float* __restrict__ bias, float* __restrict__ Cf,
    unsigned short* __restrict__ Cb, unsigned short* __restrict__ VtO,
    int Nsz, int Ksz, bool relu, int bm, int bn)
{
    __shared__ unsigned short As[64 * 32];
    __shared__ unsigned short Bs[64 * 32];
    const int t = threadIdx.x;
    const int lane = t & 63, wave = t >> 6;
    const int ln15 = lane & 15, kg = lane >> 4;
    const int wm = (wave >> 1) * 32, wn = (wave & 1) * 32;
    const int sr = t >> 2, sc = (t & 3) * 8;

    f32x4 acc[2][2];
    #pragma unroll
    for (int i = 0; i < 2; ++i)
        #pragma unroll
        for (int j = 0; j < 2; ++j) acc[i][j] = (f32x4)0.0f;

    for (int k0 = 0; k0 < Ksz; k0 += 32) {
        *(bf16x8*)&As[sr * 32 + sc] =
            *(const bf16x8*)&A[(size_t)(bm + sr) * Ksz + k0 + sc];
        *(bf16x8*)&Bs[sr * 32 + sc] =
            *(const bf16x8*)&Wt[(size_t)(bn + sr) * Ksz + k0 + sc];
        __syncthreads();
        const bf16x8 a0 = *(const bf16x8*)&As[(wm + ln15) * 32 + kg * 8];
        const bf16x8 a1 = *(const bf16x8*)&As[(wm + 16 + ln15) * 32 + kg * 8];
        const bf16x8 b0 = *(const bf16x8*)&Bs[(wn + ln15) * 32 + kg * 8];
        const bf16x8 b1 = *(const bf16x8*)&Bs[(wn + 16 + ln15) * 32 + kg * 8];
        acc[0][0] = __builtin_amdgcn_mfma_f32_16x16x32_bf16(a0, b0, acc[0][0], 0, 0, 0);
        acc[0][1] = __builtin_amdgcn_mfma_f32_16x16x32_bf16(a0, b1, acc[0][1], 0, 0, 0);
        acc[1][0] = __builtin_amdgcn_mfma_f32_16x16x32_bf16(a1, b0, acc[1][0], 0, 0, 0);
        acc[1][1] = __builtin_amdgcn_mfma_f32_16x16x32_bf16(a1, b1, acc[1][1], 0, 0, 0);
        __syncthreads();
    }

    #pragma unroll
    for (int mt = 0; mt < 2; ++mt) {
        #pragma unroll
        for (int nt = 0; nt < 2; ++nt) {
            const int col = bn + wn + nt * 16 + ln15;
            const int r0  = bm + wm + mt * 16 + kg * 4;
            const float bv = bias[col];
            if (VtO) {
                // write V^T: [B][H][32][KTOK], 4 consecutive tokens per lane
                const int bidx = r0 >> 10, tok0 = r0 & 1023;
                const int hh = col >> 5, dd = col & 31;
                ushort4 pk;
                pk.x = f2bf(acc[mt][nt][0] + bv);
                pk.y = f2bf(acc[mt][nt][1] + bv);
                pk.z = f2bf(acc[mt][nt][2] + bv);
                pk.w = f2bf(acc[mt][nt][3] + bv);
                *(ushort4*)&VtO[(((size_t)bidx * NH + hh) * HDIM + dd) * KTOK + tok0] = pk;
            } else {
                #pragma unroll
                for (int j = 0; j < 4; ++j) {
                    float v = acc[mt][nt][j] + bv;
                    if (relu) v = fmaxf(v, 0.0f);
                    const size_t o = (size_t)(r0 + j) * Nsz + col;
                    if (Cf) Cf[o] = v;
                    if (Cb) Cb[o] = f2bf(v);
                }
            }
        }
    }
}

__global__ __launch_bounds__(256) void mgemm_k(
    const unsigned short* __restrict__ A, const unsigned short* __restrict__ Wt,
    const float* __restrict__ bias, float* __restrict__ Cf,
    unsigned short* __restrict__ Cb, int Nsz, int Ksz, int relu)
{
    mgemm_body(A, Wt, bias, Cf, Cb, nullptr, Nsz, Ksz, relu != 0,
               blockIdx.y * 64, blockIdx.x * 64);
}

// Q,K -> bf16 [MROWS][256]; V -> bf16 transposed [B][H][32][KTOK]
__global__ __launch_bounds__(256) void mgemm_qkv_k(
    const unsigned short* __restrict__ qk_bf, const unsigned short* __restrict__ tgt_bf,
    const unsigned short* __restrict__ wqt, const float* __restrict__ bq,
    const unsigned short* __restrict__ wkt, const float* __restrict__ bk,
    const unsigned short* __restrict__ wvt, const float* __restrict__ bv,
    unsigned short* __restrict__ Qbf, unsigned short* __restrict__ Kbf,
    unsigned short* __restrict__ Vtg)
{
    const unsigned short* A; const unsigned short* W; const float* bi;
    unsigned short* Cb = nullptr; unsigned short* Vt = nullptr;
    if (blockIdx.z == 0)      { A = qk_bf;  W = wqt; bi = bq; Cb = Qbf; }
    else if (blockIdx.z == 1) { A = qk_bf;  W = wkt; bi = bk; Cb = Kbf; }
    else                      { A = tgt_bf; W = wvt; bi = bv; Vt = Vtg; }
    mgemm_body(A, W, bi, nullptr, Cb, Vt, DD, DD, false,
               blockIdx.y * 64, blockIdx.x * 64);
}

// ---------------------------------------------------------------------------
// MFMA flash attention: block = (q-tile 64, head, batch), 4 waves.
// Wave owns 16 q-rows; iterates 16 k-tiles of 64 tokens.
// S-tile: 4x mfma_16x16x32 (K=HDIM=32). Online softmax in D-layout
// (row=(lane>>4)*4+reg matches O accumulator). P->LDS f32 -> A-frags -> PV.
// ---------------------------------------------------------------------------
#define ATT_PSTR 68

__global__ __launch_bounds__(256) void attn_mfma_k(
    const unsigned short* __restrict__ Qbf, const unsigned short* __restrict__ Kbf,
    const unsigned short* __restrict__ Vtg, unsigned short* __restrict__ Ob)
{
    const int qt = blockIdx.x, h = blockIdx.y, b = blockIdx.z;
    const int t = threadIdx.x;
    const int w = t >> 6, lane = t & 63;
    const int ln15 = lane & 15, kg = lane >> 4;

    __shared__ unsigned short Ks[64 * 32];      // [token][d]
    __shared__ unsigned short Vts[32 * 64];     // [d][token]
    __shared__ float Ps[4][16 * ATT_PSTR];      // per-wave P rows

    const int q0 = qt * 64 + w * 16;
    const bf16x8 aQ = *(const bf16x8*)
        &Qbf[((size_t)(b * KTOK + q0 + ln15)) * DD + h * HDIM + kg * 8];

    f32x4 accO[2];
    accO[0] = (f32x4)0.0f; accO[1] = (f32x4)0.0f;
    float m_i[4], l_i[4];
    #pragma unroll
    for (int i = 0; i < 4; ++i) { m_i[i] = -1e30f; l_i[i] = 0.0f; }
    const float scale = 0.17677669529663687f;   // 1/sqrt(32)

    const int krow = t >> 2, kd0 = (t & 3) * 8;   // K staging
    const int vd = t >> 3, vt0 = (t & 7) * 8;     // V^T staging

    for (int kt = 0; kt < 16; ++kt) {
        __syncthreads();
        *(bf16x8*)&Ks[krow * 32 + kd0] = *(const bf16x8*)
            &Kbf[((size_t)(b * KTOK + kt * 64 + krow)) * DD + h * HDIM + kd0];
        *(bf16x8*)&Vts[vd * 64 + vt0] = *(const bf16x8*)
            &Vtg[(((size_t)b * NH + h) * HDIM + vd) * KTOK + kt * 64 + vt0];
        __syncthreads();

        // S = Q K^T (4 subtiles of 16 tokens)
        f32x4 s[4];
        #pragma unroll
        for (int st = 0; st < 4; ++st) {
            const bf16x8 bK = *(const bf16x8*)&Ks[(st * 16 + ln15) * 32 + kg * 8];
            s[st] = __builtin_amdgcn_mfma_f32_16x16x32_bf16(aQ, bK, (f32x4)0.0f, 0, 0, 0);
        }
        // online softmax: lane holds rows kg*4+r, cols st*16+ln15
        #pragma unroll
        for (int r = 0; r < 4; ++r) {
            float v0 = s[0][r] * scale, v1 = s[1][r] * scale;
            float v2 = s[2][r] * scale, v3 = s[3][r] * scale;
            float rm = fmaxf(fmaxf(v0, v1), fmaxf(v2, v3));
            rm = fmaxf(rm, __shfl_xor(rm, 1));
            rm = fmaxf(rm, __shfl_xor(rm, 2));
            rm = fmaxf(rm, __shfl_xor(rm, 4));
            rm = fmaxf(rm, __shfl_xor(rm, 8));
            const float mnew = fmaxf(m_i[r], rm);
            const float alpha = __expf(m_i[r] - mnew);
            v0 = __expf(v0 - mnew); v1 = __expf(v1 - mnew);
            v2 = __expf(v2 - mnew); v3 = __expf(v3 - mnew);
            float ls = v0 + v1 + v2 + v3;
            ls += __shfl_xor(ls, 1); ls += __shfl_xor(ls, 2);
            ls += __shfl_xor(ls, 4); ls += __shfl_xor(ls, 8);
            l_i[r] = l_i[r] * alpha + ls;
            m_i[r] = mnew;
            accO[0][r] *= alpha; accO[1][r] *= alpha;
            const int pr = (kg * 4 + r) * ATT_PSTR + ln15;
            Ps[w][pr +  0] = v0;
            Ps[w][pr + 16] = v1;
            Ps[w][pr + 32] = v2;
            Ps[w][pr + 48] = v3;
        }
        // O += P V  (wave-local LDS round-trip; compiler orders DS ops)
        #pragma unroll
        for (int kc = 0; kc < 2; ++kc) {
            const float* prow = &Ps[w][ln15 * ATT_PSTR + kc * 32 + kg * 8];
            const float4 pa = *(const float4*)prow;
            const float4 pb = *(const float4*)(prow + 4);
            bf16x8 aP;
            aP[0] = (short)f2bf(pa.x); aP[1] = (short)f2bf(pa.y);
            aP[2] = (short)f2bf(pa.z); aP[3] = (short)f2bf(pa.w);
            aP[4] = (short)f2bf(pb.x); aP[5] = (short)f2bf(pb.y);
            aP[6] = (short)f2bf(pb.z); aP[7] = (short)f2bf(pb.w);
            #pragma unroll
            for (int dt = 0; dt < 2; ++dt) {
                const bf16x8 bV = *(const bf16x8*)
                    &Vts[(dt * 16 + ln15) * 64 + kc * 32 + kg * 8];
                accO[dt] = __builtin_amdgcn_mfma_f32_16x16x32_bf16(aP, bV, accO[dt], 0, 0, 0);
            }
        }
    }

    #pragma unroll
    for (int dt = 0; dt < 2; ++dt)
        #pragma unroll
        for (int r = 0; r < 4; ++r) {
            const float v = accO[dt][r] / l_i[r];
            Ob[((size_t)(b * KTOK + q0 + kg * 4 + r)) * DD + h * HDIM + dt * 16 + ln15]
                = f2bf(v);
        }
}

// ---------------------------------------------------------------------------
// x = LayerNorm(A + B) * g + be  (f32 + bf16 out)
// ---------------------------------------------------------------------------
__global__ __launch_bounds__(256) void add_ln_k(
    const float* __restrict__ A, const float* __restrict__ Bv,
    const float* __restrict__ g, const float* __restrict__ be,
    float* __restrict__ outp, unsigned short* __restrict__ outp_bf)
{
    const int row = blockIdx.x, t = threadIdx.x;
    const size_t off = (size_t)row * DD + t;
    const float v = A[off] + Bv[off];
    const float mu = block_sum256(v) * (1.0f / DD);
    const float d = v - mu;
    const float var = block_sum256(d * d) * (1.0f / DD);
    const float r = d * rsqrtf(var + 1e-5f) * g[t] + be[t];
    outp[off] = r;
    outp_bf[off] = f2bf(r);
}

// LayerNorm(X + F) then ragged scatter into output
__global__ __launch_bounds__(256) void ln_scatter_k(
    const float* __restrict__ X, const float* __restrict__ F,
    const float* __restrict__ g, const float* __restrict__ be,
    const int* __restrict__ inds, const int* __restrict__ focus,
    float* __restrict__ outp)
{
    const int row = blockIdx.x, t = threadIdx.x;
    const int b = row >> 10;
    const int k = row & 1023;
    if (k >= focus[b]) return;   // uniform per block
    const size_t off = (size_t)row * DD + t;
    const float v = X[off] + F[off];
    const float mu = block_sum256(v) * (1.0f / DD);
    const float d = v - mu;
    const float var = block_sum256(d * d) * (1.0f / DD);
    const int ind = inds[b * KTOK + k];
    outp[((size_t)b * NN + ind) * DD + t] = d * rsqrtf(var + 1e-5f) * g[t] + be[t];
}

// ---------------------------------------------------------------------------
extern "C" void kernel_launch(void* const* d_in, const int* in_sizes, int n_in,
                              void* d_out, int out_size, void* d_ws, size_t ws_size,
                              hipStream_t stream)
{
    const float* query = (const float*)d_in[0];
    const float* qpos  = (const float*)d_in[1];
    const float* fg    = (const float*)d_in[6];
    const int*   focus = (const int*)d_in[7];
    const int*   finds = (const int*)d_in[8];
    const float* Wq = (const float*)d_in[9];  const float* bq = (const float*)d_in[10];
    const float* Wk = (const float*)d_in[11]; const float* bk = (const float*)d_in[12];
    const float* Wv = (const float*)d_in[13]; const float* bv = (const float*)d_in[14];
    const float* Wo = (const float*)d_in[15]; const float* bo = (const float*)d_in[16];
    const float* g1 = (const float*)d_in[17]; const float* be1 = (const float*)d_in[18];
    const float* W1 = (const float*)d_in[19]; const float* b1 = (const float*)d_in[20];
    const float* W2 = (const float*)d_in[21]; const float* b2 = (const float*)d_in[22];
    const float* g2 = (const float*)d_in[23]; const float* be2 = (const float*)d_in[24];
    const float* Wcls = (const float*)d_in[25]; const float* bcls = (const float*)d_in[26];
    float* out = (float*)d_out;

    // ---- workspace layout -------------------------------------------------
    char* p = (char*)d_ws;
    const size_t MD4 = (size_t)MROWS * DD * 4;
    const size_t MD2 = (size_t)MROWS * DD * 2;
    float* tgt  = (float*)p;  p += MD4;
    float* olin = (float*)p;  p += MD4;
    float* x    = (float*)p;  p += MD4;
    float* ff2  = (float*)p;  p += MD4;
    unsigned short* tgt_bf   = (unsigned short*)p;  p += MD2;
    unsigned short* qk_bf    = (unsigned short*)p;  p += MD2;
    unsigned short* attno_bf = (unsigned short*)p;  p += MD2;
    unsigned short* x_bf     = (unsigned short*)p;  p += MD2;
    unsigned short* Qbf      = (unsigned short*)p;  p += MD2;
    unsigned short* Kbf      = (unsigned short*)p;  p += MD2;
    unsigned short* Vtg      = (unsigned short*)p;  p += MD2;
    unsigned short* ff1_bf   = (unsigned short*)p;  p += (size_t)MROWS * FFND * 2;
    const size_t WSQ = (size_t)LAYERS * DD * DD;
    const size_t WFF = (size_t)LAYERS * DD * FFND;
    unsigned short* wqt = (unsigned short*)p;  p += WSQ * 2;
    unsigned short* wkt = (unsigned short*)p;  p += WSQ * 2;
    unsigned short* wvt = (unsigned short*)p;  p += WSQ * 2;
    unsigned short* wot = (unsigned short*)p;  p += WSQ * 2;
    unsigned short* w1t = (unsigned short*)p;  p += WFF * 2;
    unsigned short* w2t = (unsigned short*)p;  p += WFF * 2;

    // one-time weight transposes to bf16 Wt[N][K]
    transpose_cast_k<<<dim3(DD / 32, DD / 32, LAYERS), 256, 0, stream>>>(Wq, wqt, DD, DD);
    transpose_cast_k<<<dim3(DD / 32, DD / 32, LAYERS), 256, 0, stream>>>(Wk, wkt, DD, DD);
    transpose_cast_k<<<dim3(DD / 32, DD / 32, LAYERS), 256, 0, stream>>>(Wv, wvt, DD, DD);
    transpose_cast_k<<<dim3(DD / 32, DD / 32, LAYERS), 256, 0, stream>>>(Wo, wot, DD, DD);
    transpose_cast_k<<<dim3(FFND / 32, DD / 32, LAYERS), 256, 0, stream>>>(W1, w1t, DD, FFND);
    transpose_cast_k<<<dim3(DD / 32, FFND / 32, LAYERS), 256, 0, stream>>>(W2, w2t, FFND, DD);

    // output starts as query
    hipMemcpyAsync(out, query, (size_t)BB * NN * DD * sizeof(float),
                   hipMemcpyDeviceToDevice, stream);

    for (int l = 0; l < LAYERS; ++l) {
        const int* inds = finds + (size_t)l * BB * KTOK;
        gather_k<<<MROWS, 256, 0, stream>>>(out, qpos, fg, inds, Wcls, bcls,
                                            tgt, tgt_bf, qk_bf);
        mgemm_qkv_k<<<dim3(DD / 64, MROWS / 64, 3), 256, 0, stream>>>(
            qk_bf, tgt_bf,
            wqt + (size_t)l * DD * DD, bq + (size_t)l * DD,
            wkt + (size_t)l * DD * DD, bk + (size_t)l * DD,
            wvt + (size_t)l * DD * DD, bv + (size_t)l * DD,
            Qbf, Kbf, Vtg);
        attn_mfma_k<<<dim3(KTOK / 64, NH, BB), 256, 0, stream>>>(Qbf, Kbf, Vtg, attno_bf);
        mgemm_k<<<dim3(DD / 64, MROWS / 64), 256, 0, stream>>>(
            attno_bf, wot + (size_t)l * DD * DD, bo + (size_t)l * DD,
            olin, nullptr, DD, DD, 0);
        add_ln_k<<<MROWS, 256, 0, stream>>>(tgt, olin,
            g1 + (size_t)l * DD, be1 + (size_t)l * DD, x, x_bf);
        mgemm_k<<<dim3(FFND / 64, MROWS / 64), 256, 0, stream>>>(
            x_bf, w1t + (size_t)l * DD * FFND, b1 + (size_t)l * FFND,
            nullptr, ff1_bf, FFND, DD, 1);
        mgemm_k<<<dim3(DD / 64, MROWS / 64), 256, 0, stream>>>(
            ff1_bf, w2t + (size_t)l * DD * FFND, b2 + (size_t)l * DD,
            ff2, nullptr, DD, FFND, 0);
        ln_scatter_k<<<MROWS, 256, 0, stream>>>(x, ff2,
            g2 + (size_t)l * DD, be2 + (size_t)l * DD, inds, focus, out);
    }
    (void)in_sizes; (void)n_in; (void)out_size; (void)ws_size;
}